// Round 10
// baseline (816.687 us; speedup 1.0000x reference)
//
#include <hip/hip_runtime.h>
#include <hip/hip_fp16.h>
#include <hip/hip_cooperative_groups.h>

namespace cg = cooperative_groups;

// ---------------------------------------------------------------------------
// 3-layer GAT (heads=1) forward. N=100000, E=1600000, Ep=E+N, G=128,
// ND=16, ED=2, H=32.
// R25: R23 base (R24's in-register asrc reverted: it lengthened the serial
// quad-step chain; the 4B asrc gathers were cheap L2 hits). New: the 7-launch
// tail (hproj0, agg0, hproj1, agg1, hproj2, agg2, dotv) fused into ONE
// cooperative kernel k_tail with grid.sync() between phases — removes 6
// launch boundaries (gap + CU drain/ramp each). Grid sized via occupancy
// API (cooperative launch validates co-residency); on any launch error the
// exact R23 separate-kernel sequence runs instead (no regression risk).
// Carried from R23: plain cacheable rec loads; grid-stride agg; LDS {s,pe}
// edge-broadcast; quad epilogue; vout + dotv readout; colsum fused in binB;
// self-loop flag bit23; packed half2 x1/x2; LDS bucket sort binB+binC;
// hproj0/Wf; no asm waitcnt in chunk loop.
// ---------------------------------------------------------------------------

#define NBUCK_SHIFT 8
#define NBUCK_MAX 512
#define CAP 6144   // max staged edges per 256-node bucket (mean ~4350, max ~4650)
#define SLF_BIT 0x00800000u   // self-loop flag in rec.x (bit31 of sd >> 8)

// ---- fused preprocessing: [hist | (Wf + bounds)] --------------------------
__global__ void k_pre(const int* __restrict__ ei1, int* __restrict__ bucket_cnt,
                      const int* __restrict__ batch, int* __restrict__ bounds,
                      const float* __restrict__ Wne, const float* __restrict__ bne,
                      const float* __restrict__ W0, float* __restrict__ wf,
                      int n, int e, int ep, int nbH) {
    int b = blockIdx.x, t = threadIdx.x;
    if (b < nbH) {
        __shared__ int lh[NBUCK_MAX];
        lh[t] = 0; lh[t + 256] = 0;
        __syncthreads();
        int base = b * 4096;
#pragma unroll
        for (int i = 0; i < 16; ++i) {
            int gid = base + i * 256 + t;
            if (gid < ep) {
                int d = (gid < e) ? ei1[gid] : gid - e;
                atomicAdd(&lh[d >> NBUCK_SHIFT], 1);
            }
        }
        __syncthreads();
        if (lh[t]) atomicAdd(&bucket_cnt[t], lh[t]);
        if (lh[t + 256]) atomicAdd(&bucket_cnt[t + 256], lh[t + 256]);
        return;
    }
    for (int i = t; i < 288; i += 256) {
        int m = i >> 5, j = i & 31;
        float a = 0.f;
        for (int k = 0; k < 16; ++k) a += Wne[m * 16 + k] * W0[k * 32 + j];
        wf[i] = a;
    }
    if (t < 32) {
        float a = 0.f;
        for (int k = 0; k < 16; ++k) a += bne[k] * W0[k * 32 + t];
        wf[288 + t] = a;
    }
    for (int g = t; g <= 128; g += 256) {
        if (g == 128) { bounds[128] = n; continue; }
        int lo = 0, hi = n;
        while (lo < hi) {
            int mid = (lo + hi) >> 1;
            if (batch[mid] < g) lo = mid + 1; else hi = mid;
        }
        bounds[g] = lo;
    }
}

__device__ __forceinline__ float2 h2f2u(unsigned int hw) {
    __half2 hh = *reinterpret_cast<__half2*>(&hw);
    return make_float2(__low2float(hh), __high2float(hh));
}

// ---- device bodies (shared between standalone kernels and k_tail) ---------

// Layer-0 projection from raw node features: h0 = nf @ Wf + bf (grid-stride).
__device__ __forceinline__ void body_hproj0(const float* __restrict__ nf,
                                            const float* __restrict__ wf,
                                            const float* __restrict__ as_,
                                            const float* __restrict__ ad_,
                                            unsigned int* __restrict__ h2,
                                            float* __restrict__ asrc,
                                            float* __restrict__ adst, int n) {
    int g = threadIdx.x >> 5, j = threadIdx.x & 31;
    int stride = gridDim.x * 8;
    for (int node = blockIdx.x * 8 + g; node < n; node += stride) {
        const float* xr = nf + node * 9;
        float acc = wf[288 + j];
#pragma unroll
        for (int m = 0; m < 9; ++m) acc += xr[m] * wf[m * 32 + j];
        float accp = __shfl_down(acc, 1, 32);
        if ((j & 1) == 0) {
            __half2 hh = __floats2half2_rn(acc, accp);
            h2[(size_t)node * 16 + (j >> 1)] = *reinterpret_cast<unsigned int*>(&hh);
        }
        float r1 = acc * as_[j], r2 = acc * ad_[j];
#pragma unroll
        for (int off = 16; off > 0; off >>= 1) {
            r1 += __shfl_xor(r1, off, 32);
            r2 += __shfl_xor(r2, off, 32);
        }
        if (j == 0) { asrc[node] = r1; adst[node] = r2; }
    }
}

// Mid-layer projection: h = x @ W, x packed half2, W staged in sW (1024 f).
__device__ __forceinline__ void body_hproj(float* sW,
                                           const unsigned int* __restrict__ xh,
                                           const float* __restrict__ W,
                                           const float* __restrict__ as_,
                                           const float* __restrict__ ad_,
                                           unsigned int* __restrict__ h2,
                                           float* __restrict__ asrc,
                                           float* __restrict__ adst, int n) {
    for (int i = threadIdx.x; i < 1024; i += 256) sW[i] = W[i];
    __syncthreads();
    int g = threadIdx.x >> 5, j = threadIdx.x & 31;
    int stride = gridDim.x * 8;
    for (int node = blockIdx.x * 8 + g; node < n; node += stride) {
        const unsigned int* xr = xh + (size_t)node * 16;
        float acc = 0.f;
#pragma unroll
        for (int w = 0; w < 16; ++w) {
            float2 f = h2f2u(xr[w]);
            acc += f.x * sW[(2 * w) * 32 + j] + f.y * sW[(2 * w + 1) * 32 + j];
        }
        float accp = __shfl_down(acc, 1, 32);
        if ((j & 1) == 0) {
            __half2 hh = __floats2half2_rn(acc, accp);
            h2[(size_t)node * 16 + (j >> 1)] = *reinterpret_cast<unsigned int*>(&hh);
        }
        float r1 = acc * as_[j], r2 = acc * ad_[j];
#pragma unroll
        for (int off = 16; off > 0; off >>= 1) {
            r1 += __shfl_xor(r1, off, 32);
            r2 += __shfl_xor(r2, off, 32);
        }
        if (j == 0) { asrc[node] = r1; adst[node] = r2; }
    }
}

// One 4-edge step of the agg compute loop (R19/R23 form).
__device__ __forceinline__ void agg_step(const unsigned int* __restrict__ h2,
                                         const uint2* ed, int t, int sub, int woff,
                                         float& a0, float& a1, float& a2, float& a3) {
    uint2 sp = ed[t + sub];
    float p4 = __uint_as_float(sp.y);
    uint2 hv = *reinterpret_cast<const uint2*>(h2 + (((int)sp.x << 4) + woff));
    __half2 hlo = *reinterpret_cast<__half2*>(&hv.x);
    __half2 hhi = *reinterpret_cast<__half2*>(&hv.y);
    a0 = fmaf(__low2float(hlo), p4, a0);
    a1 = fmaf(__high2float(hlo), p4, a1);
    a2 = fmaf(__low2float(hhi), p4, a2);
    a3 = fmaf(__high2float(hhi), p4, a3);
}

// Fused edge-softmax + aggregation (R23 body, exact).
__device__ __forceinline__ void body_agg(uint2* sedbase,
                                         const int* __restrict__ rp,
                                         const uint2* __restrict__ rec,
                                         const float* __restrict__ asrc,
                                         const float* __restrict__ adst,
                                         const float* __restrict__ consts,
                                         const unsigned int* __restrict__ h2,
                                         const float* __restrict__ bb,
                                         unsigned int* __restrict__ xout,
                                         const float* __restrict__ wl3,
                                         float* __restrict__ vout,
                                         int n, int layer, bool store_x) {
    int g = threadIdx.x >> 5;
    int j = threadIdx.x & 31;
    int sub = j >> 3;
    int q = j & 7;
    int woff = q << 1;
    float c0 = consts[layer * 2], c1 = consts[layer * 2 + 1];
    float loopc = consts[6 + layer];
    float4 bb4 = reinterpret_cast<const float4*>(bb)[q];
    float4 wl34 = reinterpret_cast<const float4*>(wl3)[q];
    uint2* ed = sedbase + g * 32;
    int stride = gridDim.x * 8;
    for (int node = blockIdx.x * 8 + g; node < n; node += stride) {
        int r0 = rp[node], r1 = rp[node + 1];
        float adn = adst[node];
        float a0 = 0.f, a1 = 0.f, a2 = 0.f, a3 = 0.f, psum = 0.f;
        for (int c = r0; c < r1; c += 32) {
            int i = c + j;
            float pe = 0.f; unsigned int s = 0;
            if (i < r1) {
                unsigned long long rv = *reinterpret_cast<const unsigned long long*>(
                    rec + i);
                unsigned int sx = (unsigned int)rv;
                s = sx & 0x7fffffu;
                unsigned int fv = (unsigned int)(rv >> 32);
                __half2 hh = *reinterpret_cast<__half2*>(&fv);
                float ae = (sx & SLF_BIT) ? loopc
                         : fmaf(__low2float(hh), c0, __high2float(hh) * c1);
                float lg = asrc[s] + adn + ae;
                lg = lg > 0.f ? lg : 0.2f * lg;
                pe = __expf(lg);
            }
            psum += pe;
            ed[j] = make_uint2(s, __float_as_uint(pe));
            int cnt = min(32, r1 - c);
            int t = 0;
            for (; t + 8 <= cnt; t += 8) {
                agg_step(h2, ed, t, sub, woff, a0, a1, a2, a3);
                agg_step(h2, ed, t + 4, sub, woff, a0, a1, a2, a3);
            }
            if (t < cnt) { agg_step(h2, ed, t, sub, woff, a0, a1, a2, a3); t += 4; }
            if (t < cnt) { agg_step(h2, ed, t, sub, woff, a0, a1, a2, a3); }
        }
        a0 += __shfl_xor(a0, 8, 32);  a0 += __shfl_xor(a0, 16, 32);
        a1 += __shfl_xor(a1, 8, 32);  a1 += __shfl_xor(a1, 16, 32);
        a2 += __shfl_xor(a2, 8, 32);  a2 += __shfl_xor(a2, 16, 32);
        a3 += __shfl_xor(a3, 8, 32);  a3 += __shfl_xor(a3, 16, 32);
#pragma unroll
        for (int off = 16; off > 0; off >>= 1) psum += __shfl_xor(psum, off, 32);
        float inv = __builtin_amdgcn_rcpf(psum + 1e-16f);
        float r0v = fmaf(a0, inv, bb4.x);
        float r1v = fmaf(a1, inv, bb4.y);
        float r2v = fmaf(a2, inv, bb4.z);
        float r3v = fmaf(a3, inv, bb4.w);
        if (store_x && sub == 0) {
            __half2 lo = __floats2half2_rn(r0v, r1v);
            __half2 hi = __floats2half2_rn(r2v, r3v);
            uint2 wv = make_uint2(*reinterpret_cast<unsigned int*>(&lo),
                                  *reinterpret_cast<unsigned int*>(&hi));
            reinterpret_cast<uint2*>(xout)[(size_t)node * 8 + q] = wv;
        }
        float v = r0v * wl34.x + r1v * wl34.y + r2v * wl34.z + r3v * wl34.w;
        v += __shfl_xor(v, 1, 32);
        v += __shfl_xor(v, 2, 32);
        v += __shfl_xor(v, 4, 32);
        if (j == 0) vout[node] = v;
    }
}

// Readout: blocks [0,128) each reduce one graph.
__device__ __forceinline__ void body_dotv(float* red,
                                          const float* __restrict__ v0,
                                          const float* __restrict__ v1,
                                          const float* __restrict__ v2,
                                          const int* __restrict__ bounds,
                                          const float* __restrict__ bl3,
                                          float* __restrict__ out) {
    int g = blockIdx.x, t = threadIdx.x;
    if (g >= 128) return;
    int s0 = bounds[g], s1 = bounds[g + 1];
    float acc = 0.f;
    for (int i = s0 + t; i < s1; i += 256) acc += v0[i] + v1[i] + v2[i];
    red[t] = acc;
    __syncthreads();
    for (int o = 128; o > 0; o >>= 1) {
        if (t < o) red[t] += red[t + o];
        __syncthreads();
    }
    if (t == 0) {
        float c = (float)(s1 - s0);
        if (c < 1.f) c = 1.f;
        out[g] = red[0] / c + bl3[0];
    }
}

// ---- standalone wrappers (fallback path) ----------------------------------
__global__ void k_hproj0(const float* nf, const float* wf, const float* as_,
                         const float* ad_, unsigned int* h2, float* asrc,
                         float* adst, int n) {
    body_hproj0(nf, wf, as_, ad_, h2, asrc, adst, n);
}

__global__ void k_hproj(const unsigned int* xh, const float* W, const float* as_,
                        const float* ad_, unsigned int* h2, float* asrc,
                        float* adst, int n) {
    __shared__ float sW[1024];
    body_hproj(sW, xh, W, as_, ad_, h2, asrc, adst, n);
}

__global__ void k_agg(const int* rp, const uint2* rec, const float* asrc,
                      const float* adst, const float* consts,
                      const unsigned int* h2, const float* bb,
                      unsigned int* xout, const float* wl3, float* vout,
                      int n, int layer, int store_x) {
    __shared__ uint2 sed[256];
    body_agg(sed, rp, rec, asrc, adst, consts, h2, bb, xout, wl3, vout,
             n, layer, store_x != 0);
}

__global__ void k_dotv(const float* v0, const float* v1, const float* v2,
                       const int* bounds, const float* bl3, float* out) {
    __shared__ float red[256];
    body_dotv(red, v0, v1, v2, bounds, bl3, out);
}

// ---- cooperative fused tail ----------------------------------------------
struct TailArgs {
    const int* rp; const uint2* rec;
    const float* nf; const float* wf;
    unsigned int *h2a, *h2b, *x1h, *x2h;
    float *asrcA, *adstA, *asrcB, *adstB;
    const float* consts;
    const float *W1, *W2;
    const float *as0, *ad0, *as1, *ad1, *as2, *ad2;
    const float *bb0, *bb1, *bb2;
    const float* wl3;
    float *v0, *v1, *v2;
    const int* bounds; const float* bl3; float* out;
    int n;
};

__global__ void __launch_bounds__(256)
k_tail(TailArgs a) {
    __shared__ float smem[1024];
    cg::grid_group grid = cg::this_grid();
    // P0: layer-0 projection
    body_hproj0(a.nf, a.wf, a.as0, a.ad0, a.h2a, a.asrcA, a.adstA, a.n);
    grid.sync();
    // P1: layer-0 agg -> x1, v0
    body_agg((uint2*)smem, a.rp, a.rec, a.asrcA, a.adstA, a.consts, a.h2a,
             a.bb0, a.x1h, a.wl3 + 0, a.v0, a.n, 0, true);
    grid.sync();
    // P2: layer-1 projection
    body_hproj(smem, a.x1h, a.W1, a.as1, a.ad1, a.h2b, a.asrcB, a.adstB, a.n);
    grid.sync();
    // P3: layer-1 agg -> x2, v1
    body_agg((uint2*)smem, a.rp, a.rec, a.asrcB, a.adstB, a.consts, a.h2b,
             a.bb1, a.x2h, a.wl3 + 32, a.v1, a.n, 1, true);
    grid.sync();
    // P4: layer-2 projection
    body_hproj(smem, a.x2h, a.W2, a.as2, a.ad2, a.h2a, a.asrcA, a.adstA, a.n);
    grid.sync();
    // P5: layer-2 agg -> v2
    body_agg((uint2*)smem, a.rp, a.rec, a.asrcA, a.adstA, a.consts, a.h2a,
             a.bb2, nullptr, a.wl3 + 64, a.v2, a.n, 2, false);
    grid.sync();
    // P6: readout
    body_dotv(smem, a.v0, a.v1, a.v2, a.bounds, a.bl3, a.out);
}

// ---- remaining front kernels (R23 exact) ----------------------------------
__global__ void __launch_bounds__(512)
k_scan(const int* __restrict__ bucket_cnt, int* __restrict__ bucket_base,
       int* __restrict__ bcursor, int nbuck, int ep, int* __restrict__ rp, int n) {
    __shared__ int s[512];
    int t = threadIdx.x;
    int v = (t < nbuck) ? bucket_cnt[t] : 0;
    s[t] = v;
    __syncthreads();
    for (int o = 1; o < 512; o <<= 1) {
        int x = (t >= o) ? s[t - o] : 0;
        __syncthreads();
        s[t] += x;
        __syncthreads();
    }
    int ex = s[t] - v;
    if (t < nbuck) { bucket_base[t] = ex; bcursor[t] = ex; }
    if (t == 0) { bucket_base[nbuck] = ep; rp[n] = ep; }
}

__global__ void k_binB(const int* __restrict__ ei0, const int* __restrict__ ei1,
                       const float* __restrict__ ea, const float* __restrict__ We,
                       const float* __restrict__ be, int* __restrict__ bcursor,
                       uint2* __restrict__ st, float2* __restrict__ partial,
                       int e, int ep) {
    __shared__ int lh[NBUCK_MAX], lcur[NBUCK_MAX];
    int t = threadIdx.x;
    lh[t] = 0; lh[t + 256] = 0;
    __syncthreads();
    int base = blockIdx.x * 4096;
    unsigned int sd[16], fh[16];
    int bk[16];
    float w00 = We[0], w10 = We[2], w20 = We[4];
    float w01 = We[1], w11 = We[3], w21 = We[5];
    float b0 = be[0], b1 = be[1];
    float cs0 = 0.f, cs1 = 0.f;
#pragma unroll
    for (int i = 0; i < 16; ++i) {
        int gid = base + i * 256 + t;
        bk[i] = -1;
        if (gid < ep) {
            int s, d;
            if (gid < e) {
                s = ei0[gid]; d = ei1[gid];
                const float* r = ea + (size_t)gid * 3;
                float a0 = r[0], a1 = r[1], a2 = r[2];
                float f0 = a0 * w00 + a1 * w10 + a2 * w20 + b0;
                float f1 = a0 * w01 + a1 * w11 + a2 * w21 + b1;
                cs0 += f0; cs1 += f1;
                sd[i] = ((unsigned int)s << NBUCK_SHIFT) | (unsigned int)(d & 255);
                __half2 hh = __floats2half2_rn(f0, f1);
                fh[i] = *reinterpret_cast<unsigned int*>(&hh);
            } else {
                s = d = gid - e;
                sd[i] = 0x80000000u | ((unsigned int)s << NBUCK_SHIFT)
                      | (unsigned int)(d & 255);
                fh[i] = 0;
            }
            bk[i] = d >> NBUCK_SHIFT;
            atomicAdd(&lh[bk[i]], 1);
        }
    }
#pragma unroll
    for (int off = 32; off > 0; off >>= 1) {
        cs0 += __shfl_xor(cs0, off, 64);
        cs1 += __shfl_xor(cs1, off, 64);
    }
    if ((t & 63) == 0)
        partial[(blockIdx.x << 2) + (t >> 6)] = make_float2(cs0, cs1);
    __syncthreads();
    if (lh[t] > 0) lcur[t] = atomicAdd(&bcursor[t], lh[t]);
    if (lh[t + 256] > 0) lcur[t + 256] = atomicAdd(&bcursor[t + 256], lh[t + 256]);
    __syncthreads();
#pragma unroll
    for (int i = 0; i < 16; ++i) {
        if (bk[i] >= 0) {
            int pos = atomicAdd(&lcur[bk[i]], 1);
            st[pos] = make_uint2(sd[i], fh[i]);
        }
    }
}

__global__ void __launch_bounds__(512)
k_binC(const uint2* __restrict__ st, const int* __restrict__ bucket_base,
       int* __restrict__ rp, uint2* __restrict__ rec, int n, int nbuck,
       const float* __restrict__ We0, const float* __restrict__ ae0,
       const float* __restrict__ We1, const float* __restrict__ ae1,
       const float* __restrict__ We2, const float* __restrict__ ae2,
       const float2* __restrict__ partial, int nw, float einv,
       float* __restrict__ consts) {
    int k = blockIdx.x, t = threadIdx.x;
    if (k == nbuck) {
        __shared__ float r0[512], r1[512];
        float m0 = 0.f, m1 = 0.f;
        for (int i = t; i < nw; i += 512) {
            float2 v = partial[i];
            m0 += v.x; m1 += v.y;
        }
        r0[t] = m0; r1[t] = m1;
        __syncthreads();
        for (int o = 256; o > 0; o >>= 1) {
            if (t < o) { r0[t] += r0[t + o]; r1[t] += r1[t + o]; }
            __syncthreads();
        }
        if (t == 0) {
            float fm0 = r0[0] * einv, fm1 = r1[0] * einv;
            const float* We[3] = {We0, We1, We2};
            const float* ae[3] = {ae0, ae1, ae2};
            for (int l = 0; l < 3; ++l) {
                float c0 = 0.f, c1 = 0.f;
                for (int j = 0; j < 32; ++j) {
                    c0 += We[l][j] * ae[l][j];
                    c1 += We[l][32 + j] * ae[l][j];
                }
                consts[l * 2 + 0] = c0;
                consts[l * 2 + 1] = c1;
                consts[6 + l] = fm0 * c0 + fm1 * c1;
            }
        }
        return;
    }
    __shared__ int nh[256], ns[256];
    __shared__ uint2 rs[CAP];
    int s0 = bucket_base[k], s1 = bucket_base[k + 1];
    int cnt = s1 - s0;
    uint2 lv[12];
    if (t < 256) nh[t] = 0;
    __syncthreads();
#pragma unroll
    for (int u = 0; u < 12; ++u) {
        int i = s0 + u * 512 + t;
        if (i < s1) {
            uint2 v = st[i];
            lv[u] = v;
            atomicAdd(&nh[v.x & 255], 1);
        }
    }
    __syncthreads();
    if (t < 256) ns[t] = nh[t];
    __syncthreads();
    for (int o = 1; o < 256; o <<= 1) {
        int add = 0;
        if (t < 256 && t >= o) add = ns[t - o];
        __syncthreads();
        if (t < 256) ns[t] += add;
        __syncthreads();
    }
    int node0 = k << NBUCK_SHIFT;
    if (t < 256) {
        int startl = ns[t] - nh[t];
        if (node0 + t < n) rp[node0 + t] = s0 + startl;
        nh[t] = startl;
    }
    __syncthreads();
#pragma unroll
    for (int u = 0; u < 12; ++u) {
        int i = s0 + u * 512 + t;
        if (i < s1) {
            uint2 v = lv[u];
            int pos = atomicAdd(&nh[v.x & 255], 1);
            uint2 r = make_uint2(v.x >> NBUCK_SHIFT, v.y);
            if (pos < CAP) rs[pos] = r;
            else rec[s0 + pos] = r;
        }
    }
    __syncthreads();
    int m = cnt < CAP ? cnt : CAP;
    for (int i = t; i < m; i += 512)
        rec[s0 + i] = rs[i];
}

extern "C" void kernel_launch(void* const* d_in, const int* in_sizes, int n_in,
                              void* d_out, int out_size, void* d_ws, size_t ws_size,
                              hipStream_t stream) {
    (void)n_in; (void)out_size; (void)ws_size;
    const float* nf    = (const float*)d_in[0];
    const int*   ei    = (const int*)d_in[1];
    const float* ea    = (const float*)d_in[2];
    const int*   batch = (const int*)d_in[3];
    const float* W_ne  = (const float*)d_in[4];
    const float* b_ne  = (const float*)d_in[5];
    const float* W_ee  = (const float*)d_in[6];
    const float* b_ee  = (const float*)d_in[7];
    const float* W_l3  = (const float*)d_in[8];
    const float* b_l3  = (const float*)d_in[9];
    const float *Wl[3], *asl[3], *adl[3], *Wel[3], *ael[3], *bbl[3];
    for (int l = 0; l < 3; ++l) {
        Wl[l]  = (const float*)d_in[10 + 6 * l];
        asl[l] = (const float*)d_in[11 + 6 * l];
        adl[l] = (const float*)d_in[12 + 6 * l];
        Wel[l] = (const float*)d_in[13 + 6 * l];
        ael[l] = (const float*)d_in[14 + 6 * l];
        bbl[l] = (const float*)d_in[15 + 6 * l];
    }

    const int n  = in_sizes[3];        // 100000
    const int e  = in_sizes[2] / 3;    // 1600000
    const int ep = e + n;
    const int* ei0 = ei;
    const int* ei1 = ei + e;
    const int nbuck = (n + 255) >> NBUCK_SHIFT;   // 391

    char* w = (char*)d_ws;
    size_t off = 0;
    auto alloc = [&](size_t b) { size_t o = off; off = (off + b + 255) & ~(size_t)255; return o; };
    unsigned int* x1h     = (unsigned int*)(w + alloc((size_t)n * 16 * 4));
    unsigned int* x2h     = (unsigned int*)(w + alloc((size_t)n * 16 * 4));
    unsigned int* h2a     = (unsigned int*)(w + alloc((size_t)n * 16 * 4));
    unsigned int* h2b     = (unsigned int*)(w + alloc((size_t)n * 16 * 4));
    float*        asrcA   = (float*)(w + alloc((size_t)n * 4));
    float*        adstA   = (float*)(w + alloc((size_t)n * 4));
    float*        asrcB   = (float*)(w + alloc((size_t)n * 4));
    float*        adstB   = (float*)(w + alloc((size_t)n * 4));
    float*        v0      = (float*)(w + alloc((size_t)n * 4));
    float*        v1      = (float*)(w + alloc((size_t)n * 4));
    float*        v2      = (float*)(w + alloc((size_t)n * 4));
    uint2*        st      = (uint2*)(w + alloc((size_t)ep * 8));
    uint2*        rec     = (uint2*)(w + alloc((size_t)ep * 8));
    int*          rp      = (int*)(w + alloc((size_t)(n + 1) * 4));
    int*          bcnt    = (int*)(w + alloc(NBUCK_MAX * 4));
    int*          bbase   = (int*)(w + alloc((NBUCK_MAX + 1) * 4));
    int*          bcur    = (int*)(w + alloc(NBUCK_MAX * 4));
    float2*       partial = (float2*)(w + alloc((size_t)8192 * 8));
    float*        consts  = (float*)(w + alloc(256));
    int*          bounds  = (int*)(w + alloc(129 * 4));
    float*        wfbuf   = (float*)(w + alloc(320 * 4));

    hipMemsetAsync(bcnt, 0, NBUCK_MAX * 4, stream);

    int nbH = (ep + 4095) / 4096;        // 416
    int nw  = nbH * 4;                   // colsum partial slots (from binB)
    int nbN = (n + 7) / 8;               // 12500

    k_pre<<<nbH + 1, 256, 0, stream>>>(ei1, bcnt, batch, bounds,
                                       W_ne, b_ne, Wl[0], wfbuf, n, e, ep, nbH);
    k_scan<<<1, 512, 0, stream>>>(bcnt, bbase, bcur, nbuck, ep, rp, n);
    k_binB<<<nbH, 256, 0, stream>>>(ei0, ei1, ea, W_ee, b_ee, bcur, st,
                                    partial, e, ep);
    k_binC<<<nbuck + 1, 512, 0, stream>>>(st, bbase, rp, rec, n, nbuck,
                                          Wel[0], ael[0], Wel[1], ael[1],
                                          Wel[2], ael[2], partial, nw,
                                          1.0f / (float)e, consts);

    // ---- tail: cooperative fused path with separate-kernel fallback -------
    static int coopBlocks = -2;   // -2 uninit, -1 unsupported, >0 grid size
    if (coopBlocks == -2) {
        int dev = 0;
        hipGetDevice(&dev);
        int cuCount = 0, coopSup = 0, perCU = 0;
        hipDeviceGetAttribute(&cuCount, hipDeviceAttributeMultiprocessorCount, dev);
        hipDeviceGetAttribute(&coopSup, hipDeviceAttributeCooperativeLaunch, dev);
        hipError_t oe = hipOccupancyMaxActiveBlocksPerMultiprocessor(
            &perCU, k_tail, 256, 0);
        int cap = (oe == hipSuccess && coopSup) ? perCU * cuCount : 0;
        coopBlocks = (cap >= 512) ? (cap < 2048 ? cap : 2048) : -1;
    }

    bool coopDone = false;
    if (coopBlocks > 0) {
        TailArgs ta;
        ta.rp = rp; ta.rec = rec; ta.nf = nf; ta.wf = wfbuf;
        ta.h2a = h2a; ta.h2b = h2b; ta.x1h = x1h; ta.x2h = x2h;
        ta.asrcA = asrcA; ta.adstA = adstA; ta.asrcB = asrcB; ta.adstB = adstB;
        ta.consts = consts; ta.W1 = Wl[1]; ta.W2 = Wl[2];
        ta.as0 = asl[0]; ta.ad0 = adl[0];
        ta.as1 = asl[1]; ta.ad1 = adl[1];
        ta.as2 = asl[2]; ta.ad2 = adl[2];
        ta.bb0 = bbl[0]; ta.bb1 = bbl[1]; ta.bb2 = bbl[2];
        ta.wl3 = W_l3; ta.v0 = v0; ta.v1 = v1; ta.v2 = v2;
        ta.bounds = bounds; ta.bl3 = b_l3; ta.out = (float*)d_out;
        ta.n = n;
        void* kargs[] = { &ta };
        hipError_t le = hipLaunchCooperativeKernel(
            (const void*)k_tail, dim3(coopBlocks), dim3(256), kargs, 0, stream);
        if (le == hipSuccess) coopDone = true;
        else { coopBlocks = -1; (void)hipGetLastError(); }
    }
    if (!coopDone) {
        int nbA = 2048;
        k_hproj0<<<nbN, 256, 0, stream>>>(nf, wfbuf, asl[0], adl[0],
                                          h2a, asrcA, adstA, n);
        k_agg<<<nbA, 256, 0, stream>>>(rp, rec, asrcA, adstA, consts, h2a,
                                       bbl[0], x1h, W_l3 + 0, v0, n, 0, 1);
        k_hproj<<<nbN, 256, 0, stream>>>(x1h, Wl[1], asl[1], adl[1],
                                         h2b, asrcB, adstB, n);
        k_agg<<<nbA, 256, 0, stream>>>(rp, rec, asrcB, adstB, consts, h2b,
                                       bbl[1], x2h, W_l3 + 32, v1, n, 1, 1);
        k_hproj<<<nbN, 256, 0, stream>>>(x2h, Wl[2], asl[2], adl[2],
                                         h2a, asrcA, adstA, n);
        k_agg<<<nbA, 256, 0, stream>>>(rp, rec, asrcA, adstA, consts, h2a,
                                       bbl[2], nullptr, W_l3 + 64, v2, n, 2, 0);
        k_dotv<<<128, 256, 0, stream>>>(v0, v1, v2, bounds, b_l3, (float*)d_out);
    }
}

// Round 11
// 311.703 us; speedup vs baseline: 2.6201x; 2.6201x over previous
//
#include <hip/hip_runtime.h>
#include <hip/hip_fp16.h>

// ---------------------------------------------------------------------------
// 3-layer GAT (heads=1) forward. N=100000, E=1600000, Ep=E+N, G=128,
// ND=16, ED=2, H=32.
// R26: exact revert to R23 (measured best, 312.7us). R25's cooperative
// fused tail regressed 2.6x: grid.sync() on a 2048-block grid across 8
// non-coherent XCD L2s costs tens of us per barrier, and the fused kernel's
// 52 VGPR dropped occupancy 70->48%. Kernel boundaries ARE the cheap grid
// barrier on this chip.
// R23 = R19 structure + plain cacheable rec loads (NT removed so agg1/agg2
// hit the 256MB L3 for the 13.6MB rec stream instead of re-fetching HBM).
// Session ledger: wins R16 (quad-slice agg), R18/R19 (grid-stride + LDS
// {s,pe} broadcast + no asm barrier), R23 (cacheable rec). Failed: R17
// (128-slot atomic readout), R20 (GEMV fusion: DS-pipe + occupancy), R21
// (node pairing: divergence), R22 (scattered 8B writes: 64B write-allocate
// -> 103MB), R24 (in-register asrc: serial chain), R25 (coop fusion).
// Aggs are latency-bound (VALU ~2.5%, HBM ~15%, occupancy 70%, full wave
// residency) on dependent random gathers; structure at practical floor.
// ---------------------------------------------------------------------------

#define NBUCK_SHIFT 8
#define NBUCK_MAX 512
#define CAP 6144   // max staged edges per 256-node bucket (mean ~4350, max ~4650)
#define SLF_BIT 0x00800000u   // self-loop flag in rec.x (bit31 of sd >> 8)

// ---- fused preprocessing: [hist | (Wf + bounds)] --------------------------
__global__ void k_pre(const int* __restrict__ ei1, int* __restrict__ bucket_cnt,
                      const int* __restrict__ batch, int* __restrict__ bounds,
                      const float* __restrict__ Wne, const float* __restrict__ bne,
                      const float* __restrict__ W0, float* __restrict__ wf,
                      int n, int e, int ep, int nbH) {
    int b = blockIdx.x, t = threadIdx.x;
    if (b < nbH) {
        __shared__ int lh[NBUCK_MAX];
        lh[t] = 0; lh[t + 256] = 0;
        __syncthreads();
        int base = b * 4096;
#pragma unroll
        for (int i = 0; i < 16; ++i) {
            int gid = base + i * 256 + t;
            if (gid < ep) {
                int d = (gid < e) ? ei1[gid] : gid - e;
                atomicAdd(&lh[d >> NBUCK_SHIFT], 1);
            }
        }
        __syncthreads();
        if (lh[t]) atomicAdd(&bucket_cnt[t], lh[t]);
        if (lh[t + 256]) atomicAdd(&bucket_cnt[t + 256], lh[t + 256]);
        return;
    }
    // last block: fused layer-0 weights Wf = Wne@W0 (9x32), bf = bne@W0,
    // then graph bounds by binary search.
    for (int i = t; i < 288; i += 256) {
        int m = i >> 5, j = i & 31;
        float a = 0.f;
        for (int k = 0; k < 16; ++k) a += Wne[m * 16 + k] * W0[k * 32 + j];
        wf[i] = a;
    }
    if (t < 32) {
        float a = 0.f;
        for (int k = 0; k < 16; ++k) a += bne[k] * W0[k * 32 + t];
        wf[288 + t] = a;
    }
    for (int g = t; g <= 128; g += 256) {
        if (g == 128) { bounds[128] = n; continue; }
        int lo = 0, hi = n;
        while (lo < hi) {
            int mid = (lo + hi) >> 1;
            if (batch[mid] < g) lo = mid + 1; else hi = mid;
        }
        bounds[g] = lo;
    }
}

// Layer-0 projection straight from raw node features (x0 never exists):
// h0 = nf @ Wf + bf.  h stored packed half2.
__global__ void k_hproj0(const float* __restrict__ nf, const float* __restrict__ wf,
                         const float* __restrict__ as_, const float* __restrict__ ad_,
                         unsigned int* __restrict__ h2, float* __restrict__ asrc,
                         float* __restrict__ adst, int n) {
    int node = blockIdx.x * 8 + (threadIdx.x >> 5);
    int j = threadIdx.x & 31;
    if (node >= n) return;
    const float* xr = nf + node * 9;
    float acc = wf[288 + j];
#pragma unroll
    for (int m = 0; m < 9; ++m) acc += xr[m] * wf[m * 32 + j];
    float accp = __shfl_down(acc, 1, 32);
    if ((j & 1) == 0) {
        __half2 hh = __floats2half2_rn(acc, accp);
        h2[(size_t)node * 16 + (j >> 1)] = *reinterpret_cast<unsigned int*>(&hh);
    }
    float r1 = acc * as_[j], r2 = acc * ad_[j];
#pragma unroll
    for (int off = 16; off > 0; off >>= 1) {
        r1 += __shfl_xor(r1, off, 32);
        r2 += __shfl_xor(r2, off, 32);
    }
    if (j == 0) { asrc[node] = r1; adst[node] = r2; }
}

__device__ __forceinline__ float2 h2f2u(unsigned int hw) {
    __half2 hh = *reinterpret_cast<__half2*>(&hw);
    return make_float2(__low2float(hh), __high2float(hh));
}

// Mid-layer projection: h = x @ W, x packed half2 (16 words/node), W in LDS.
__global__ void k_hproj(const unsigned int* __restrict__ xh, const float* __restrict__ W,
                        const float* __restrict__ as_, const float* __restrict__ ad_,
                        unsigned int* __restrict__ h2, float* __restrict__ asrc,
                        float* __restrict__ adst, int n) {
    __shared__ float sW[1024];
    for (int i = threadIdx.x; i < 1024; i += 256) sW[i] = W[i];
    __syncthreads();
    int node = blockIdx.x * 8 + (threadIdx.x >> 5);
    int j = threadIdx.x & 31;
    if (node >= n) return;
    const unsigned int* xr = xh + (size_t)node * 16;
    float acc = 0.f;
#pragma unroll
    for (int w = 0; w < 16; ++w) {
        float2 f = h2f2u(xr[w]);
        acc += f.x * sW[(2 * w) * 32 + j] + f.y * sW[(2 * w + 1) * 32 + j];
    }
    float accp = __shfl_down(acc, 1, 32);
    if ((j & 1) == 0) {
        __half2 hh = __floats2half2_rn(acc, accp);
        h2[(size_t)node * 16 + (j >> 1)] = *reinterpret_cast<unsigned int*>(&hh);
    }
    float r1 = acc * as_[j], r2 = acc * ad_[j];
#pragma unroll
    for (int off = 16; off > 0; off >>= 1) {
        r1 += __shfl_xor(r1, off, 32);
        r2 += __shfl_xor(r2, off, 32);
    }
    if (j == 0) { asrc[node] = r1; adst[node] = r2; }
}

// Bucket-base scan (1 block).
__global__ void __launch_bounds__(512)
k_scan(const int* __restrict__ bucket_cnt, int* __restrict__ bucket_base,
       int* __restrict__ bcursor, int nbuck, int ep, int* __restrict__ rp, int n) {
    __shared__ int s[512];
    int t = threadIdx.x;
    int v = (t < nbuck) ? bucket_cnt[t] : 0;
    s[t] = v;
    __syncthreads();
    for (int o = 1; o < 512; o <<= 1) {
        int x = (t >= o) ? s[t - o] : 0;
        __syncthreads();
        s[t] += x;
        __syncthreads();
    }
    int ex = s[t] - v;
    if (t < nbuck) { bucket_base[t] = ex; bcursor[t] = ex; }
    if (t == 0) { bucket_base[nbuck] = ep; rp[n] = ep; }
}

// Phase B: stage edges grouped by bucket (8B uint2 {sd, half2}) AND compute
// ef column-sum partials (per-wave, unique slots, no atomics). Self-loop recs
// get flag bit31 in sd (no consts dependency here).
__global__ void k_binB(const int* __restrict__ ei0, const int* __restrict__ ei1,
                       const float* __restrict__ ea, const float* __restrict__ We,
                       const float* __restrict__ be, int* __restrict__ bcursor,
                       uint2* __restrict__ st, float2* __restrict__ partial,
                       int e, int ep) {
    __shared__ int lh[NBUCK_MAX], lcur[NBUCK_MAX];
    int t = threadIdx.x;
    lh[t] = 0; lh[t + 256] = 0;
    __syncthreads();
    int base = blockIdx.x * 4096;
    unsigned int sd[16], fh[16];
    int bk[16];
    float w00 = We[0], w10 = We[2], w20 = We[4];
    float w01 = We[1], w11 = We[3], w21 = We[5];
    float b0 = be[0], b1 = be[1];
    float cs0 = 0.f, cs1 = 0.f;
#pragma unroll
    for (int i = 0; i < 16; ++i) {
        int gid = base + i * 256 + t;
        bk[i] = -1;
        if (gid < ep) {
            int s, d;
            if (gid < e) {
                s = ei0[gid]; d = ei1[gid];
                const float* r = ea + (size_t)gid * 3;
                float a0 = r[0], a1 = r[1], a2 = r[2];
                float f0 = a0 * w00 + a1 * w10 + a2 * w20 + b0;
                float f1 = a0 * w01 + a1 * w11 + a2 * w21 + b1;
                cs0 += f0; cs1 += f1;
                sd[i] = ((unsigned int)s << NBUCK_SHIFT) | (unsigned int)(d & 255);
                __half2 hh = __floats2half2_rn(f0, f1);
                fh[i] = *reinterpret_cast<unsigned int*>(&hh);
            } else {
                s = d = gid - e;
                sd[i] = 0x80000000u | ((unsigned int)s << NBUCK_SHIFT)
                      | (unsigned int)(d & 255);
                fh[i] = 0;
            }
            bk[i] = d >> NBUCK_SHIFT;
            atomicAdd(&lh[bk[i]], 1);
        }
    }
    // per-wave colsum partial (real edges only)
#pragma unroll
    for (int off = 32; off > 0; off >>= 1) {
        cs0 += __shfl_xor(cs0, off, 64);
        cs1 += __shfl_xor(cs1, off, 64);
    }
    if ((t & 63) == 0)
        partial[(blockIdx.x << 2) + (t >> 6)] = make_float2(cs0, cs1);
    __syncthreads();
    if (lh[t] > 0) lcur[t] = atomicAdd(&bcursor[t], lh[t]);
    if (lh[t + 256] > 0) lcur[t + 256] = atomicAdd(&bcursor[t + 256], lh[t + 256]);
    __syncthreads();
#pragma unroll
    for (int i = 0; i < 16; ++i) {
        if (bk[i] >= 0) {
            int pos = atomicAdd(&lcur[bk[i]], 1);
            st[pos] = make_uint2(sd[i], fh[i]);
        }
    }
}

// Phase C: blocks [0,nbuck) sort one bucket each (single-pass, recs in
// registers); block nbuck reduces colsum partials -> consts
// ([0..5]=We@ae per layer, [6..8]=self-loop logit per layer).
__global__ void __launch_bounds__(512)
k_binC(const uint2* __restrict__ st, const int* __restrict__ bucket_base,
       int* __restrict__ rp, uint2* __restrict__ rec, int n, int nbuck,
       const float* __restrict__ We0, const float* __restrict__ ae0,
       const float* __restrict__ We1, const float* __restrict__ ae1,
       const float* __restrict__ We2, const float* __restrict__ ae2,
       const float2* __restrict__ partial, int nw, float einv,
       float* __restrict__ consts) {
    int k = blockIdx.x, t = threadIdx.x;
    if (k == nbuck) {
        __shared__ float r0[512], r1[512];
        float m0 = 0.f, m1 = 0.f;
        for (int i = t; i < nw; i += 512) {
            float2 v = partial[i];
            m0 += v.x; m1 += v.y;
        }
        r0[t] = m0; r1[t] = m1;
        __syncthreads();
        for (int o = 256; o > 0; o >>= 1) {
            if (t < o) { r0[t] += r0[t + o]; r1[t] += r1[t + o]; }
            __syncthreads();
        }
        if (t == 0) {
            float fm0 = r0[0] * einv, fm1 = r1[0] * einv;
            const float* We[3] = {We0, We1, We2};
            const float* ae[3] = {ae0, ae1, ae2};
            for (int l = 0; l < 3; ++l) {
                float c0 = 0.f, c1 = 0.f;
                for (int j = 0; j < 32; ++j) {
                    c0 += We[l][j] * ae[l][j];
                    c1 += We[l][32 + j] * ae[l][j];
                }
                consts[l * 2 + 0] = c0;
                consts[l * 2 + 1] = c1;
                consts[6 + l] = fm0 * c0 + fm1 * c1;
            }
        }
        return;
    }
    __shared__ int nh[256], ns[256];
    __shared__ uint2 rs[CAP];
    int s0 = bucket_base[k], s1 = bucket_base[k + 1];
    int cnt = s1 - s0;
    uint2 lv[12];
    if (t < 256) nh[t] = 0;
    __syncthreads();
#pragma unroll
    for (int u = 0; u < 12; ++u) {
        int i = s0 + u * 512 + t;
        if (i < s1) {
            uint2 v = st[i];
            lv[u] = v;
            atomicAdd(&nh[v.x & 255], 1);
        }
    }
    __syncthreads();
    if (t < 256) ns[t] = nh[t];
    __syncthreads();
    for (int o = 1; o < 256; o <<= 1) {
        int add = 0;
        if (t < 256 && t >= o) add = ns[t - o];
        __syncthreads();
        if (t < 256) ns[t] += add;
        __syncthreads();
    }
    int node0 = k << NBUCK_SHIFT;
    if (t < 256) {
        int startl = ns[t] - nh[t];
        if (node0 + t < n) rp[node0 + t] = s0 + startl;
        nh[t] = startl;
    }
    __syncthreads();
#pragma unroll
    for (int u = 0; u < 12; ++u) {
        int i = s0 + u * 512 + t;
        if (i < s1) {
            uint2 v = lv[u];
            int pos = atomicAdd(&nh[v.x & 255], 1);
            uint2 r = make_uint2(v.x >> NBUCK_SHIFT, v.y);  // flag lands at bit23
            if (pos < CAP) rs[pos] = r;
            else rec[s0 + pos] = r;      // overflow fallback (never in practice)
        }
    }
    __syncthreads();
    int m = cnt < CAP ? cnt : CAP;
    for (int i = t; i < m; i += 512)
        rec[s0 + i] = rs[i];
}

// One 4-edge step: lane j covers edge t+(j>>3), features 4(j&7)..+3.
// {s,pe} come from the group's LDS row (4 distinct 8B addrs, 8-lane
// broadcast each -> conflict-free). Padding slots have pe=0, s=0.
__device__ __forceinline__ void agg_step(const unsigned int* __restrict__ h2,
                                         const uint2* ed, int t, int sub, int woff,
                                         float& a0, float& a1, float& a2, float& a3) {
    uint2 sp = ed[t + sub];
    float p4 = __uint_as_float(sp.y);
    uint2 hv = *reinterpret_cast<const uint2*>(h2 + (((int)sp.x << 4) + woff));
    __half2 hlo = *reinterpret_cast<__half2*>(&hv.x);
    __half2 hhi = *reinterpret_cast<__half2*>(&hv.y);
    a0 = fmaf(__low2float(hlo), p4, a0);
    a1 = fmaf(__high2float(hlo), p4, a1);
    a2 = fmaf(__low2float(hhi), p4, a2);
    a3 = fmaf(__high2float(hhi), p4, a3);
}

// Fused edge-softmax + aggregation, 32-lane group per dst node, grid-stride.
// rec.x: bit23 = self-loop flag (use consts[6+layer] logit), low bits = src.
// Epilogue in quad layout; per-node scalar to vout (no atomics).
// Plain (cacheable) rec loads so later layers hit L3.
template <bool STORE_X>
__global__ void k_agg(const int* __restrict__ rp, const uint2* __restrict__ rec,
                      const float* __restrict__ asrc, const float* __restrict__ adst,
                      const float* __restrict__ consts, const unsigned int* __restrict__ h2,
                      const float* __restrict__ bb, unsigned int* __restrict__ xout,
                      const float* __restrict__ wl3, float* __restrict__ vout,
                      int n, int layer) {
    __shared__ uint2 sed[8][32];
    int g = threadIdx.x >> 5;
    int j = threadIdx.x & 31;
    int sub = j >> 3;              // which edge of the quad
    int q = j & 7;                 // feature quad
    int woff = q << 1;             // half2-word offset: features 4q..4q+3
    float c0 = consts[layer * 2], c1 = consts[layer * 2 + 1];
    float loopc = consts[6 + layer];
    float4 bb4 = reinterpret_cast<const float4*>(bb)[q];
    float4 wl34 = reinterpret_cast<const float4*>(wl3)[q];
    uint2* ed = sed[g];
    int stride = gridDim.x * 8;
    for (int node = blockIdx.x * 8 + g; node < n; node += stride) {
        int r0 = rp[node], r1 = rp[node + 1];
        float adn = adst[node];
        float a0 = 0.f, a1 = 0.f, a2 = 0.f, a3 = 0.f, psum = 0.f;
        for (int c = r0; c < r1; c += 32) {
            int i = c + j;
            float pe = 0.f; unsigned int s = 0;
            if (i < r1) {
                unsigned long long rv = *reinterpret_cast<const unsigned long long*>(
                    rec + i);
                unsigned int sx = (unsigned int)rv;
                s = sx & 0x7fffffu;
                unsigned int fv = (unsigned int)(rv >> 32);
                __half2 hh = *reinterpret_cast<__half2*>(&fv);
                float ae = (sx & SLF_BIT) ? loopc
                         : fmaf(__low2float(hh), c0, __high2float(hh) * c1);
                float lg = asrc[s] + adn + ae;
                lg = lg > 0.f ? lg : 0.2f * lg;
                pe = __expf(lg);
            }
            psum += pe;
            ed[j] = make_uint2(s, __float_as_uint(pe));
            int cnt = min(32, r1 - c);
            int t = 0;
            for (; t + 8 <= cnt; t += 8) {
                agg_step(h2, ed, t, sub, woff, a0, a1, a2, a3);
                agg_step(h2, ed, t + 4, sub, woff, a0, a1, a2, a3);
            }
            if (t < cnt) { agg_step(h2, ed, t, sub, woff, a0, a1, a2, a3); t += 4; }
            if (t < cnt) { agg_step(h2, ed, t, sub, woff, a0, a1, a2, a3); }
        }
        // combine the 4 sub-copies (lanes j, j^8, j^16, j^24 share a quad)
        a0 += __shfl_xor(a0, 8, 32);  a0 += __shfl_xor(a0, 16, 32);
        a1 += __shfl_xor(a1, 8, 32);  a1 += __shfl_xor(a1, 16, 32);
        a2 += __shfl_xor(a2, 8, 32);  a2 += __shfl_xor(a2, 16, 32);
        a3 += __shfl_xor(a3, 8, 32);  a3 += __shfl_xor(a3, 16, 32);
#pragma unroll
        for (int off = 16; off > 0; off >>= 1) psum += __shfl_xor(psum, off, 32);
        float inv = __builtin_amdgcn_rcpf(psum + 1e-16f);
        float r0v = fmaf(a0, inv, bb4.x);
        float r1v = fmaf(a1, inv, bb4.y);
        float r2v = fmaf(a2, inv, bb4.z);
        float r3v = fmaf(a3, inv, bb4.w);
        if (STORE_X) {
            if (sub == 0) {
                __half2 lo = __floats2half2_rn(r0v, r1v);
                __half2 hi = __floats2half2_rn(r2v, r3v);
                uint2 wv = make_uint2(*reinterpret_cast<unsigned int*>(&lo),
                                      *reinterpret_cast<unsigned int*>(&hi));
                reinterpret_cast<uint2*>(xout)[(size_t)node * 8 + q] = wv;
            }
        }
        float v = r0v * wl34.x + r1v * wl34.y + r2v * wl34.z + r3v * wl34.w;
        v += __shfl_xor(v, 1, 32);
        v += __shfl_xor(v, 2, 32);
        v += __shfl_xor(v, 4, 32);
        if (j == 0) vout[node] = v;
    }
}

// Readout: one block per graph, sums the three per-node scalars. 1.2MB total.
__global__ void k_dotv(const float* __restrict__ v0, const float* __restrict__ v1,
                       const float* __restrict__ v2, const int* __restrict__ bounds,
                       const float* __restrict__ bl3, float* __restrict__ out) {
    __shared__ float red[256];
    int g = blockIdx.x, t = threadIdx.x;
    int s0 = bounds[g], s1 = bounds[g + 1];
    float acc = 0.f;
    for (int i = s0 + t; i < s1; i += 256) acc += v0[i] + v1[i] + v2[i];
    red[t] = acc;
    __syncthreads();
    for (int o = 128; o > 0; o >>= 1) {
        if (t < o) red[t] += red[t + o];
        __syncthreads();
    }
    if (t == 0) {
        float c = (float)(s1 - s0);
        if (c < 1.f) c = 1.f;
        out[g] = red[0] / c + bl3[0];
    }
}

extern "C" void kernel_launch(void* const* d_in, const int* in_sizes, int n_in,
                              void* d_out, int out_size, void* d_ws, size_t ws_size,
                              hipStream_t stream) {
    (void)n_in; (void)out_size; (void)ws_size;
    const float* nf    = (const float*)d_in[0];
    const int*   ei    = (const int*)d_in[1];
    const float* ea    = (const float*)d_in[2];
    const int*   batch = (const int*)d_in[3];
    const float* W_ne  = (const float*)d_in[4];
    const float* b_ne  = (const float*)d_in[5];
    const float* W_ee  = (const float*)d_in[6];
    const float* b_ee  = (const float*)d_in[7];
    const float* W_l3  = (const float*)d_in[8];
    const float* b_l3  = (const float*)d_in[9];
    const float *Wl[3], *asl[3], *adl[3], *Wel[3], *ael[3], *bbl[3];
    for (int l = 0; l < 3; ++l) {
        Wl[l]  = (const float*)d_in[10 + 6 * l];
        asl[l] = (const float*)d_in[11 + 6 * l];
        adl[l] = (const float*)d_in[12 + 6 * l];
        Wel[l] = (const float*)d_in[13 + 6 * l];
        ael[l] = (const float*)d_in[14 + 6 * l];
        bbl[l] = (const float*)d_in[15 + 6 * l];
    }

    const int n  = in_sizes[3];        // 100000
    const int e  = in_sizes[2] / 3;    // 1600000
    const int ep = e + n;
    const int* ei0 = ei;
    const int* ei1 = ei + e;
    const int nbuck = (n + 255) >> NBUCK_SHIFT;   // 391

    char* w = (char*)d_ws;
    size_t off = 0;
    auto alloc = [&](size_t b) { size_t o = off; off = (off + b + 255) & ~(size_t)255; return o; };
    unsigned int* x1h     = (unsigned int*)(w + alloc((size_t)n * 16 * 4));
    unsigned int* x2h     = (unsigned int*)(w + alloc((size_t)n * 16 * 4));
    unsigned int* h2a     = (unsigned int*)(w + alloc((size_t)n * 16 * 4));
    unsigned int* h2b     = (unsigned int*)(w + alloc((size_t)n * 16 * 4));
    float*        asrcA   = (float*)(w + alloc((size_t)n * 4));
    float*        adstA   = (float*)(w + alloc((size_t)n * 4));
    float*        asrcB   = (float*)(w + alloc((size_t)n * 4));
    float*        adstB   = (float*)(w + alloc((size_t)n * 4));
    float*        v0      = (float*)(w + alloc((size_t)n * 4));
    float*        v1      = (float*)(w + alloc((size_t)n * 4));
    float*        v2      = (float*)(w + alloc((size_t)n * 4));
    uint2*        st      = (uint2*)(w + alloc((size_t)ep * 8));
    uint2*        rec     = (uint2*)(w + alloc((size_t)ep * 8));
    int*          rp      = (int*)(w + alloc((size_t)(n + 1) * 4));
    int*          bcnt    = (int*)(w + alloc(NBUCK_MAX * 4));
    int*          bbase   = (int*)(w + alloc((NBUCK_MAX + 1) * 4));
    int*          bcur    = (int*)(w + alloc(NBUCK_MAX * 4));
    float2*       partial = (float2*)(w + alloc((size_t)8192 * 8));
    float*        consts  = (float*)(w + alloc(256));
    int*          bounds  = (int*)(w + alloc(129 * 4));
    float*        wfbuf   = (float*)(w + alloc(320 * 4));

    hipMemsetAsync(bcnt, 0, NBUCK_MAX * 4, stream);

    int nbH = (ep + 4095) / 4096;        // 416
    int nw  = nbH * 4;                   // colsum partial slots (from binB)
    int nbN = (n + 7) / 8;               // 12500
    int nbA = 2048;                      // grid-stride agg blocks

    k_pre<<<nbH + 1, 256, 0, stream>>>(ei1, bcnt, batch, bounds,
                                       W_ne, b_ne, Wl[0], wfbuf, n, e, ep, nbH);
    k_hproj0<<<nbN, 256, 0, stream>>>(nf, wfbuf, asl[0], adl[0],
                                      h2a, asrcA, adstA, n);
    k_scan<<<1, 512, 0, stream>>>(bcnt, bbase, bcur, nbuck, ep, rp, n);
    k_binB<<<nbH, 256, 0, stream>>>(ei0, ei1, ea, W_ee, b_ee, bcur, st,
                                    partial, e, ep);
    k_binC<<<nbuck + 1, 512, 0, stream>>>(st, bbase, rp, rec, n, nbuck,
                                          Wel[0], ael[0], Wel[1], ael[1],
                                          Wel[2], ael[2], partial, nw,
                                          1.0f / (float)e, consts);

    // layer 0: h2a/A -> x1h, v0
    k_agg<true><<<nbA, 256, 0, stream>>>(rp, rec, asrcA, adstA, consts, h2a,
                                         bbl[0], x1h, W_l3 + 0, v0, n, 0);
    k_hproj<<<nbN, 256, 0, stream>>>(x1h, Wl[1], asl[1], adl[1], h2b, asrcB, adstB, n);
    // layer 1: h2b/B -> x2h, v1
    k_agg<true><<<nbA, 256, 0, stream>>>(rp, rec, asrcB, adstB, consts, h2b,
                                         bbl[1], x2h, W_l3 + 32, v1, n, 1);
    k_hproj<<<nbN, 256, 0, stream>>>(x2h, Wl[2], asl[2], adl[2], h2a, asrcA, adstA, n);
    // layer 2: h2a/A -> v2 only
    k_agg<false><<<nbA, 256, 0, stream>>>(rp, rec, asrcA, adstA, consts, h2a,
                                          bbl[2], nullptr, W_l3 + 64, v2, n, 2);
    k_dotv<<<128, 256, 0, stream>>>(v0, v1, v2, bounds, b_l3, (float*)d_out);
}